// Round 7
// baseline (145.057 us; speedup 1.0000x reference)
//
#include <hip/hip_runtime.h>

// MultiHeadAttention  B=2, T=2048, D=1024, NH=16, HD=64
// Round 7: round-6 pipeline with the pair-mapping bug fixed (a = v5, bijective
// coverage of all 32 q-tiles). Depth-3 prefetch quad-buffered LDS in flash and
// GEMM; XCD-local bh mapping; defer-max; hoisted LDS offsets.

typedef __bf16 bf16x8 __attribute__((ext_vector_type(8)));
typedef float f32x4 __attribute__((ext_vector_type(4)));
typedef unsigned short ushortx8 __attribute__((ext_vector_type(8)));
typedef unsigned short ushortx4 __attribute__((ext_vector_type(4)));

#define T_SEQ 2048
#define NHEAD 16
#define HDIM 64
#define DMODEL 1024

__device__ inline unsigned short f2bf(float f) {
  unsigned int u = __builtin_bit_cast(unsigned int, f);
  unsigned int r = (u + 0x7fffu + ((u >> 16) & 1u)) >> 16;
  return (unsigned short)r;
}

__device__ inline void gl16(const unsigned short* g, unsigned short* l) {
  __builtin_amdgcn_global_load_lds(
      (const __attribute__((address_space(1))) unsigned int*)g,
      (__attribute__((address_space(3))) unsigned int*)l, 16, 0, 0);
}

// x (NX elems) then Wq,Wk,Wv,Wo (NXD each) -> contiguous bf16 at out
__global__ void cast_all(const float* __restrict__ x, const float* __restrict__ w0,
                         const float* __restrict__ w1, const float* __restrict__ w2,
                         const float* __restrict__ w3, unsigned short* __restrict__ out) {
  const int NX = 2 * T_SEQ * DMODEL;
  int i = (blockIdx.x * 256 + threadIdx.x) * 4;
  const float* src;
  int off;
  if (i < NX) {
    src = x; off = i;
  } else {
    const int j = i - NX;
    const int sel = j >> 20;
    off = j & ((1 << 20) - 1);
    src = sel == 0 ? w0 : sel == 1 ? w1 : sel == 2 ? w2 : w3;
  }
  float4 v = *reinterpret_cast<const float4*>(src + off);
  ushortx4 o;
  o[0] = f2bf(v.x); o[1] = f2bf(v.y); o[2] = f2bf(v.z); o[3] = f2bf(v.w);
  *reinterpret_cast<ushortx4*>(out + i) = o;
}

// 128x128 bf16 MFMA mainloop, quad-buffered LDS, prefetch depth 3.
__device__ __forceinline__ void gemm_core(
    const unsigned short* __restrict__ A, const unsigned short* __restrict__ Bw,
    int K, int m0, int n0, f32x4 acc[4][4]) {
  __shared__ unsigned short As[4][4096];
  __shared__ unsigned short Bs[4][4096];
  const int tid = threadIdx.x;
  const int lane = tid & 63, wid = tid >> 6;
  const int wr = wid >> 1, wc = wid & 1;
  const int lr = lane & 15, lg = lane >> 4;
  const unsigned short* ga0 = A + (size_t)(m0 + (tid >> 2)) * K + (tid & 3) * 8;
  const unsigned short* gb0 = Bw + (size_t)(n0 + (tid >> 2)) * K + (tid & 3) * 8;

#define STAGE_G(buf, k0_)                                          \
  do {                                                             \
    gl16(ga0 + (k0_), &As[buf][tid * 8]);                          \
    gl16(ga0 + (size_t)64 * K + (k0_), &As[buf][2048 + tid * 8]);  \
    gl16(gb0 + (k0_), &Bs[buf][tid * 8]);                          \
    gl16(gb0 + (size_t)64 * K + (k0_), &Bs[buf][2048 + tid * 8]);  \
  } while (0)

  const int NI = K >> 5;  // k-iters (K=1024 -> 32, >=4 assumed)
  STAGE_G(0, 0);
  STAGE_G(1, 32);
  STAGE_G(2, 64);  // 12 outstanding

  for (int i = 0; i < NI; ++i) {
    const int cb = i & 3;
    const int ahead = NI - 1 - i;
    if (ahead >= 3) {
      STAGE_G((i + 3) & 3, (i + 3) * 32);                // 16 outstanding
      asm volatile("s_waitcnt vmcnt(12)" ::: "memory");  // stage i landed
    } else if (ahead == 2) {
      asm volatile("s_waitcnt vmcnt(8)" ::: "memory");
    } else if (ahead == 1) {
      asm volatile("s_waitcnt vmcnt(4)" ::: "memory");
    } else {
      asm volatile("s_waitcnt vmcnt(0)" ::: "memory");
    }
    __builtin_amdgcn_s_barrier();
    asm volatile("" ::: "memory");

    bf16x8 af[4], bfr[4];
#pragma unroll
    for (int t = 0; t < 4; ++t) {
      af[t]  = *reinterpret_cast<const bf16x8*>(&As[cb][(wr * 64 + t * 16 + lr) * 32 + lg * 8]);
      bfr[t] = *reinterpret_cast<const bf16x8*>(&Bs[cb][(wc * 64 + t * 16 + lr) * 32 + lg * 8]);
    }
#pragma unroll
    for (int mi = 0; mi < 4; ++mi)
#pragma unroll
      for (int ni = 0; ni < 4; ++ni)
        acc[mi][ni] = __builtin_amdgcn_mfma_f32_16x16x32_bf16(af[mi], bfr[ni], acc[mi][ni], 0, 0, 0);

    asm volatile("" ::: "memory");
    __builtin_amdgcn_s_barrier();  // reads of cb done -> iter i+1 may overwrite it
  }
#undef STAGE_G
}

// Fused Q/K/V projections: z=0 Q (scaled 1/8*log2e, [b,h,t,d]); z=1 K; z=2 V^T ([b,h,d,t]).
__global__ __launch_bounds__(256) void gemm_qkv(
    const unsigned short* __restrict__ xb, const unsigned short* __restrict__ Wall,
    unsigned short* __restrict__ Qb, unsigned short* __restrict__ Kb,
    unsigned short* __restrict__ Vtb) {
  const int z = blockIdx.z;
  const int m0 = blockIdx.y * 128, n0 = blockIdx.x * 128;
  f32x4 acc[4][4] = {};
  gemm_core(xb, Wall + (size_t)z * (DMODEL * DMODEL), DMODEL, m0, n0, acc);

  const int tid = threadIdx.x, lane = tid & 63, wid = tid >> 6;
  const int wr = wid >> 1, wc = wid & 1, lr = lane & 15, lg = lane >> 4;
  const int mb = m0 + wr * 64, nb = n0 + wc * 64;
  unsigned short* out = z == 0 ? Qb : z == 1 ? Kb : Vtb;
  const float scale = z == 0 ? 0.125f * 1.44269504089f : 1.0f;  // exp2 domain
#pragma unroll
  for (int mi = 0; mi < 4; ++mi)
#pragma unroll
    for (int ni = 0; ni < 4; ++ni) {
      const int col = nb + ni * 16 + lr;
      const int h = col >> 6, d = col & (HDIM - 1);
#pragma unroll
      for (int j = 0; j < 4; ++j) {
        const int row = mb + mi * 16 + lg * 4 + j;
        const int b = row >> 11, t = row & (T_SEQ - 1);
        const float v = acc[mi][ni][j] * scale;
        if (z < 2)
          out[(((size_t)(b * NHEAD + h) * T_SEQ + t) << 6) + d] = f2bf(v);
        else
          out[(((size_t)(b * NHEAD + h) * HDIM + d) << 11) + t] = f2bf(v);
      }
    }
}

__global__ __launch_bounds__(256) void gemm_proj(
    const unsigned short* __restrict__ Ob, const unsigned short* __restrict__ Wob,
    float* __restrict__ out, const float* __restrict__ bias) {
  const int m0 = blockIdx.y * 128, n0 = blockIdx.x * 128;
  f32x4 acc[4][4] = {};
  gemm_core(Ob, Wob, DMODEL, m0, n0, acc);

  const int tid = threadIdx.x, lane = tid & 63, wid = tid >> 6;
  const int wr = wid >> 1, wc = wid & 1, lr = lane & 15, lg = lane >> 4;
  const int mb = m0 + wr * 64, nb = n0 + wc * 64;
#pragma unroll
  for (int mi = 0; mi < 4; ++mi)
#pragma unroll
    for (int ni = 0; ni < 4; ++ni) {
      const int col = nb + ni * 16 + lr;
      const float bv = bias[col];
#pragma unroll
      for (int j = 0; j < 4; ++j) {
        const int row = mb + mi * 16 + lg * 4 + j;
        out[(size_t)row * DMODEL + col] = acc[mi][ni][j] + bv;
      }
    }
}

// Flash attention, causal, complementary q-tile pairing, quad-buffered staging.
// Q (pre-scaled by 0.125*log2e), K: [b,h,t,d]; Vt: [b,h,d,t]; O: [b,t,D].
// 1D grid 512: bh = (bid&7)*4 + ((bid>>3)&3) -> each XCD (bid&7) sees 4 bh's
// (2MB K/V, fits its 4MB L2). Pair index v5 = bid>>5: a = v5 (0..15),
// btile = 31-v5 (16..31) -- bijective, covers all 32 q-tiles exactly once.
// 8 waves: waves 0-3 -> q-tile a, waves 4-7 -> btile. Shared K/V stream kt=0..btile.
// Lane (lr,lg) holds S^T[k=kb+c*16+lg*4+j][q=qg+lr]; PV: O^T = mfma(V^T, P)
// with shared k-slot map k(ks,e,lg) = (ks*2+(e>>2))*16 + lg*4 + (e&3).
__global__ __launch_bounds__(512, 4) void flash_attn(
    const unsigned short* __restrict__ Q, const unsigned short* __restrict__ Kg,
    const unsigned short* __restrict__ Vt, unsigned short* __restrict__ O) {
  __shared__ unsigned short Ks[4][4096];  // [64][64] elems per buffer
  __shared__ unsigned short Vs[4][4096];
  const int tid = threadIdx.x, lane = tid & 63, wid = tid >> 6;
  const int lr = lane & 15, lg = lane >> 4;
  const int bid = blockIdx.x;
  const int bh = (bid & 7) * 4 + ((bid >> 3) & 3);
  const int a = (bid >> 5) & 15;  // 0..15
  const int btile = 31 - a;       // 16..31
  const int myq = (wid < 4) ? a : btile;
  const int qg = myq * 64 + (wid & 3) * 16;
  const size_t base = (size_t)bh * (T_SEQ * HDIM);
  const int q = qg + lr;

  // Q fragment (B-operand); drain so vmcnt bookkeeping below is exact.
  bf16x8 qf[2];
#pragma unroll
  for (int h = 0; h < 2; ++h)
    qf[h] = *reinterpret_cast<const bf16x8*>(Q + base + (size_t)(qg + lr) * HDIM + h * 32 + lg * 8);
  asm volatile("s_waitcnt vmcnt(0)" ::: "memory");

  // staging: 512 threads cover one 64x64 tile per gl16 (row tid>>3, chunk tid&7),
  // source chunk pre-XORed by row&7 (both-sides swizzle).
  const int srow = tid >> 3;
  const int schk = ((tid & 7) ^ (srow & 7)) * 8;
  const unsigned short* kst = Kg + base + (size_t)srow * HDIM + schk;
  const unsigned short* vst = Vt + base + (size_t)srow * T_SEQ + schk;

#define STAGE(buf, kt_)                                \
  do {                                                 \
    const int kb_ = (kt_) * 64;                        \
    gl16(kst + (size_t)kb_ * HDIM, &Ks[buf][tid * 8]); \
    gl16(vst + kb_, &Vs[buf][tid * 8]);                \
  } while (0)

  // hoisted swizzled LDS offsets (loop-invariant, statically indexed)
  int koff[4][2];
#pragma unroll
  for (int c = 0; c < 4; ++c)
#pragma unroll
    for (int h = 0; h < 2; ++h)
      koff[c][h] = (c * 16 + lr) * 64 + (((h * 4 + lg) ^ (lr & 7)) * 8);
  int voff[4][2][2];
#pragma unroll
  for (int dt = 0; dt < 4; ++dt)
#pragma unroll
    for (int ks = 0; ks < 2; ++ks) {
      const int g0 = (ks * 4 + (lg >> 1)) ^ (lr & 7);
      const int g1 = (ks * 4 + 2 + (lg >> 1)) ^ (lr & 7);
      voff[dt][ks][0] = (dt * 16 + lr) * 64 + g0 * 8 + (lg & 1) * 4;
      voff[dt][ks][1] = (dt * 16 + lr) * 64 + g1 * 8 + (lg & 1) * 4;
    }

  float mrun = -INFINITY, lrun = 0.f;
  f32x4 acc[4] = {};  // acc[dt][j] = O^T[d=dt*16+lg*4+j][q]
  const int nt = btile + 1;  // >= 17

  STAGE(0, 0);
  STAGE(1, 1);
  STAGE(2, 2);  // 6 outstanding

  for (int kt = 0; kt < nt; ++kt) {
    const int cb = kt & 3;
    const int ahead = btile - kt;
    if (ahead >= 3) {
      STAGE((kt + 3) & 3, kt + 3);                      // 8 outstanding
      asm volatile("s_waitcnt vmcnt(6)" ::: "memory");  // stage kt landed
    } else if (ahead == 2) {
      asm volatile("s_waitcnt vmcnt(4)" ::: "memory");
    } else if (ahead == 1) {
      asm volatile("s_waitcnt vmcnt(2)" ::: "memory");
    } else {
      asm volatile("s_waitcnt vmcnt(0)" ::: "memory");
    }
    __builtin_amdgcn_s_barrier();
    asm volatile("" ::: "memory");

    if (kt <= myq) {  // wave-uniform
      const int kb = kt * 64;
      // ---- QK: S^T = K Q^T ----
      f32x4 s[4] = {};
      bf16x8 kf[4][2];
#pragma unroll
      for (int c = 0; c < 4; ++c)
#pragma unroll
        for (int h = 0; h < 2; ++h)
          kf[c][h] = *reinterpret_cast<const bf16x8*>(&Ks[cb][koff[c][h]]);
#pragma unroll
      for (int c = 0; c < 4; ++c)
#pragma unroll
        for (int h = 0; h < 2; ++h)
          s[c] = __builtin_amdgcn_mfma_f32_16x16x32_bf16(kf[c][h], qf[h], s[c], 0, 0, 0);

      // ---- mask (diagonal tile only) ----
      if (kt == myq) {
#pragma unroll
        for (int c = 0; c < 4; ++c)
#pragma unroll
          for (int j = 0; j < 4; ++j) {
            const int k = kb + c * 16 + lg * 4 + j;
            if (k > q) s[c][j] = -INFINITY;
          }
      }
      // ---- lane-local row max (exp2 domain) ----
      float tm = -INFINITY;
#pragma unroll
      for (int c = 0; c < 4; ++c)
#pragma unroll
        for (int j = 0; j < 4; ++j) tm = fmaxf(tm, s[c][j]);
      tm = fmaxf(tm, __shfl_xor(tm, 16, 64));
      tm = fmaxf(tm, __shfl_xor(tm, 32, 64));
      // ---- defer-max: rescale only when the running max grew > 8 ----
      if (!__all(tm <= mrun + 8.f)) {
        const float mnew = fmaxf(mrun, tm);
        const float fac = exp2f(mrun - mnew);
        lrun *= fac;
#pragma unroll
        for (int dt = 0; dt < 4; ++dt)
#pragma unroll
          for (int j = 0; j < 4; ++j) acc[dt][j] *= fac;  // fac lane-local
        mrun = mnew;
      }
      float tsum = 0.f;
#pragma unroll
      for (int c = 0; c < 4; ++c)
#pragma unroll
        for (int j = 0; j < 4; ++j) {
          const float p = exp2f(s[c][j] - mrun);  // <= 2^8; exp2(-inf)=0 kills masked
          s[c][j] = p;
          tsum += p;
        }
      tsum += __shfl_xor(tsum, 16, 64);
      tsum += __shfl_xor(tsum, 32, 64);
      lrun += tsum;

      // ---- pack P in-register ----
      bf16x8 pb[2];
#pragma unroll
      for (int ks = 0; ks < 2; ++ks) {
        bf16x8 t8;
#pragma unroll
        for (int e = 0; e < 8; ++e) t8[e] = (__bf16)s[ks * 2 + (e >> 2)][e & 3];
        pb[ks] = t8;
      }
      // ---- PV: O^T += V^T * P (V frags from swizzled LDS, two b64 each) ----
#pragma unroll
      for (int dt = 0; dt < 4; ++dt) {
#pragma unroll
        for (int ks = 0; ks < 2; ++ks) {
          uint2 vlo = *reinterpret_cast<const uint2*>(&Vs[cb][voff[dt][ks][0]]);
          uint2 vhi = *reinterpret_cast<const uint2*>(&Vs[cb][voff[dt][ks][1]]);
          uint4 u;
          u.x = vlo.x; u.y = vlo.y; u.z = vhi.x; u.w = vhi.y;
          bf16x8 vf = __builtin_bit_cast(bf16x8, u);
          acc[dt] = __builtin_amdgcn_mfma_f32_16x16x32_bf16(vf, pb[ks], acc[dt], 0, 0, 0);
        }
      }
    }
    asm volatile("" ::: "memory");
    __builtin_amdgcn_s_barrier();  // all reads of cb done -> next iter may overwrite
  }
#undef STAGE

  // epilogue: O[b, q, h*64 + d]; lrun lane-local
  const int b = bh >> 4, h = bh & (NHEAD - 1);
  const float inv = 1.0f / lrun;
  unsigned short* orow = O + (((size_t)(b * T_SEQ + q)) << 10) + h * HDIM + lg * 4;
#pragma unroll
  for (int dt = 0; dt < 4; ++dt) {
    ushortx4 o4;
#pragma unroll
    for (int j = 0; j < 4; ++j) o4[j] = f2bf(acc[dt][j] * inv);
    *reinterpret_cast<ushortx4*>(orow + dt * 16) = o4;
  }
}

extern "C" void kernel_launch(void* const* d_in, const int* in_sizes, int n_in,
                              void* d_out, int out_size, void* d_ws, size_t ws_size,
                              hipStream_t stream) {
  const float* x  = (const float*)d_in[0];
  const float* Wq = (const float*)d_in[1];
  const float* Wk = (const float*)d_in[2];
  const float* Wv = (const float*)d_in[3];
  const float* Wo = (const float*)d_in[4];
  const float* bo = (const float*)d_in[5];
  float* out = (float*)d_out;

  const int M = 2 * T_SEQ;          // 4096
  const int NXD = DMODEL * DMODEL;  // 1048576
  const int NX = M * DMODEL;        // 4194304

  unsigned short* ws = (unsigned short*)d_ws;
  unsigned short* xb  = ws;
  unsigned short* Wqb = xb + NX;                 // Wq,Wk,Wv,Wo contiguous
  unsigned short* Wob = Wqb + 3 * (size_t)NXD;
  unsigned short* Qb  = Wqb + 4 * (size_t)NXD;   // [b,h,t,d], pre-scaled 0.125*log2e
  unsigned short* Kbf = Qb + NX;                 // [b,h,t,d]
  unsigned short* Vtb = Kbf + NX;                // [b,h,d,t]
  unsigned short* Ob  = Vtb + NX;                // [b,t,D]

  cast_all<<<(NX + 4 * NXD) / 1024, 256, 0, stream>>>(x, Wq, Wk, Wv, Wo, xb);

  dim3 gq(DMODEL / 128, M / 128, 3);
  gemm_qkv<<<gq, 256, 0, stream>>>(xb, Wqb, Qb, Kbf, Vtb);

  flash_attn<<<512, 512, 0, stream>>>(Qb, Kbf, Vtb, Ob);

  dim3 gg(DMODEL / 128, M / 128);
  gemm_proj<<<gg, 256, 0, stream>>>(Ob, Wob, out, bo);
}

// Round 8
// 116.999 us; speedup vs baseline: 1.2398x; 1.2398x over previous
//
#include <hip/hip_runtime.h>

// MultiHeadAttention  B=2, T=2048, D=1024, NH=16, HD=64
// Round 8: GEMM reverted to m97 single-buffer (16KB LDS, 5 blocks/CU) after
// the quad-buffer occupancy regression; chunk-XOR LDS swizzle (both-sides,
// cancels); V projection computed transposed (A=Wv, B=x) so V^T stores are
// coalesced. Flash unchanged from round 7.

typedef __bf16 bf16x8 __attribute__((ext_vector_type(8)));
typedef float f32x4 __attribute__((ext_vector_type(4)));
typedef unsigned short ushortx8 __attribute__((ext_vector_type(8)));
typedef unsigned short ushortx4 __attribute__((ext_vector_type(4)));

#define T_SEQ 2048
#define NHEAD 16
#define HDIM 64
#define DMODEL 1024

__device__ inline unsigned short f2bf(float f) {
  unsigned int u = __builtin_bit_cast(unsigned int, f);
  unsigned int r = (u + 0x7fffu + ((u >> 16) & 1u)) >> 16;
  return (unsigned short)r;
}

__device__ inline void gl16(const unsigned short* g, unsigned short* l) {
  __builtin_amdgcn_global_load_lds(
      (const __attribute__((address_space(1))) unsigned int*)g,
      (__attribute__((address_space(3))) unsigned int*)l, 16, 0, 0);
}

// x (NX elems) then Wq,Wk,Wv,Wo (NXD each) -> contiguous bf16 at out
__global__ void cast_all(const float* __restrict__ x, const float* __restrict__ w0,
                         const float* __restrict__ w1, const float* __restrict__ w2,
                         const float* __restrict__ w3, unsigned short* __restrict__ out) {
  const int NX = 2 * T_SEQ * DMODEL;
  int i = (blockIdx.x * 256 + threadIdx.x) * 4;
  const float* src;
  int off;
  if (i < NX) {
    src = x; off = i;
  } else {
    const int j = i - NX;
    const int sel = j >> 20;
    off = j & ((1 << 20) - 1);
    src = sel == 0 ? w0 : sel == 1 ? w1 : sel == 2 ? w2 : w3;
  }
  float4 v = *reinterpret_cast<const float4*>(src + off);
  ushortx4 o;
  o[0] = f2bf(v.x); o[1] = f2bf(v.y); o[2] = f2bf(v.z); o[3] = f2bf(v.w);
  *reinterpret_cast<ushortx4*>(out + i) = o;
}

// 128x128 bf16 MFMA mainloop — m97 structure: single 16KB LDS, 2 barriers/iter,
// global_load_lds w16, chunk-XOR swizzle (source chunk ^= row&3; read chunk
// lg^(row&3)) which cancels: each lane still holds k-chunk lg. 4-way conflicts.
// acc[mi][ni][j]: C row = m0+(wid>>1)*64+mi*16+lg*4+j, col = n0+(wid&1)*64+ni*16+lr
__device__ __forceinline__ void gemm_core(
    const unsigned short* __restrict__ A, const unsigned short* __restrict__ Bw,
    int K, int m0, int n0, f32x4 acc[4][4]) {
  __shared__ unsigned short As[4096];
  __shared__ unsigned short Bs[4096];
  const int tid = threadIdx.x;
  const int lane = tid & 63, wid = tid >> 6;
  const int wr = wid >> 1, wc = wid & 1;
  const int lr = lane & 15, lg = lane >> 4;
  const int srow = tid >> 2;                       // 0..63 (and +64)
  const int scs = ((tid & 3) ^ (srow & 3)) * 8;    // pre-swizzled source chunk
  const unsigned short* ga0 = A + (size_t)(m0 + srow) * K + scs;
  const unsigned short* gb0 = Bw + (size_t)(n0 + srow) * K + scs;
  unsigned short* la0 = As + tid * 8;
  unsigned short* lb0 = Bs + tid * 8;
  const int rca = (lg ^ (lr & 3)) * 8;             // read chunk (A/B frag rows ≡ lr mod 4)

  for (int k0 = 0; k0 < K; k0 += 32) {
    __syncthreads();  // previous frag reads done before overwrite
    gl16(ga0 + k0, la0);
    gl16(ga0 + (size_t)64 * K + k0, la0 + 2048);
    gl16(gb0 + k0, lb0);
    gl16(gb0 + (size_t)64 * K + k0, lb0 + 2048);
    __syncthreads();  // compiler drains vmcnt before s_barrier

    bf16x8 af[4], bfr[4];
#pragma unroll
    for (int t = 0; t < 4; ++t) {
      af[t]  = *reinterpret_cast<const bf16x8*>(&As[(wr * 64 + t * 16 + lr) * 32 + rca]);
      bfr[t] = *reinterpret_cast<const bf16x8*>(&Bs[(wc * 64 + t * 16 + lr) * 32 + rca]);
    }
#pragma unroll
    for (int mi = 0; mi < 4; ++mi)
#pragma unroll
      for (int ni = 0; ni < 4; ++ni)
        acc[mi][ni] = __builtin_amdgcn_mfma_f32_16x16x32_bf16(af[mi], bfr[ni], acc[mi][ni], 0, 0, 0);
  }
}

// Fused Q/K/V projections, grid (256, 3).
// z=0: Q = x@Wq^T scaled (M=4096, N=1024) -> [b,h,t,d]
// z=1: K = x@Wk^T              (M=4096, N=1024) -> [b,h,t,d]
// z=2: V^T = Wv@x^T            (M=1024, N=4096) -> [b,h,d,t]  (coalesced t-stores)
__global__ __launch_bounds__(256) void gemm_qkv(
    const unsigned short* __restrict__ xb, const unsigned short* __restrict__ Wall,
    unsigned short* __restrict__ Qb, unsigned short* __restrict__ Kb,
    unsigned short* __restrict__ Vtb) {
  const int z = blockIdx.y;
  const int bid = blockIdx.x;
  int m0, n0;
  const unsigned short* A;
  const unsigned short* Bw;
  if (z < 2) {
    n0 = (bid & 7) * 128; m0 = (bid >> 3) * 128;
    A = xb; Bw = Wall + (size_t)z * (DMODEL * DMODEL);
  } else {
    m0 = (bid & 7) * 128; n0 = (bid >> 3) * 128;
    A = Wall + (size_t)2 * (DMODEL * DMODEL); Bw = xb;
  }
  f32x4 acc[4][4] = {};
  gemm_core(A, Bw, DMODEL, m0, n0, acc);

  const int tid = threadIdx.x, lane = tid & 63, wid = tid >> 6;
  const int wr = wid >> 1, wc = wid & 1, lr = lane & 15, lg = lane >> 4;
  const int mb = m0 + wr * 64, nb = n0 + wc * 64;
  const float scale = z == 0 ? 0.125f * 1.44269504089f : 1.0f;  // exp2 domain
#pragma unroll
  for (int mi = 0; mi < 4; ++mi)
#pragma unroll
    for (int ni = 0; ni < 4; ++ni) {
      const int col = nb + ni * 16 + lr;
#pragma unroll
      for (int j = 0; j < 4; ++j) {
        const int row = mb + mi * 16 + lg * 4 + j;
        const float v = acc[mi][ni][j] * scale;
        if (z < 2) {
          const int b = row >> 11, t = row & (T_SEQ - 1);
          const int h = col >> 6, d = col & (HDIM - 1);
          unsigned short* out = z == 0 ? Qb : Kb;
          out[(((size_t)(b * NHEAD + h) * T_SEQ + t) << 6) + d] = f2bf(v);
        } else {
          const int h = row >> 6, d = row & (HDIM - 1);
          const int b = col >> 11, t = col & (T_SEQ - 1);
          Vtb[(((size_t)(b * NHEAD + h) * HDIM + d) << 11) + t] = f2bf(v);
        }
      }
    }
}

__global__ __launch_bounds__(256) void gemm_proj(
    const unsigned short* __restrict__ Ob, const unsigned short* __restrict__ Wob,
    float* __restrict__ out, const float* __restrict__ bias) {
  const int m0 = blockIdx.y * 128, n0 = blockIdx.x * 128;
  f32x4 acc[4][4] = {};
  gemm_core(Ob, Wob, DMODEL, m0, n0, acc);

  const int tid = threadIdx.x, lane = tid & 63, wid = tid >> 6;
  const int wr = wid >> 1, wc = wid & 1, lr = lane & 15, lg = lane >> 4;
  const int mb = m0 + wr * 64, nb = n0 + wc * 64;
#pragma unroll
  for (int mi = 0; mi < 4; ++mi)
#pragma unroll
    for (int ni = 0; ni < 4; ++ni) {
      const int col = nb + ni * 16 + lr;
      const float bv = bias[col];
#pragma unroll
      for (int j = 0; j < 4; ++j) {
        const int row = mb + mi * 16 + lg * 4 + j;
        out[(size_t)row * DMODEL + col] = acc[mi][ni][j] + bv;
      }
    }
}

// Flash attention (unchanged from round 7): causal, complementary q-tile pairing,
// quad-buffered staging, defer-max, XCD-local bh mapping.
__global__ __launch_bounds__(512, 4) void flash_attn(
    const unsigned short* __restrict__ Q, const unsigned short* __restrict__ Kg,
    const unsigned short* __restrict__ Vt, unsigned short* __restrict__ O) {
  __shared__ unsigned short Ks[4][4096];  // [64][64] elems per buffer
  __shared__ unsigned short Vs[4][4096];
  const int tid = threadIdx.x, lane = tid & 63, wid = tid >> 6;
  const int lr = lane & 15, lg = lane >> 4;
  const int bid = blockIdx.x;
  const int bh = (bid & 7) * 4 + ((bid >> 3) & 3);
  const int a = (bid >> 5) & 15;  // 0..15
  const int btile = 31 - a;       // 16..31
  const int myq = (wid < 4) ? a : btile;
  const int qg = myq * 64 + (wid & 3) * 16;
  const size_t base = (size_t)bh * (T_SEQ * HDIM);
  const int q = qg + lr;

  bf16x8 qf[2];
#pragma unroll
  for (int h = 0; h < 2; ++h)
    qf[h] = *reinterpret_cast<const bf16x8*>(Q + base + (size_t)(qg + lr) * HDIM + h * 32 + lg * 8);
  asm volatile("s_waitcnt vmcnt(0)" ::: "memory");

  const int srow = tid >> 3;
  const int schk = ((tid & 7) ^ (srow & 7)) * 8;
  const unsigned short* kst = Kg + base + (size_t)srow * HDIM + schk;
  const unsigned short* vst = Vt + base + (size_t)srow * T_SEQ + schk;

#define STAGE(buf, kt_)                                \
  do {                                                 \
    const int kb_ = (kt_) * 64;                        \
    gl16(kst + (size_t)kb_ * HDIM, &Ks[buf][tid * 8]); \
    gl16(vst + kb_, &Vs[buf][tid * 8]);                \
  } while (0)

  int koff[4][2];
#pragma unroll
  for (int c = 0; c < 4; ++c)
#pragma unroll
    for (int h = 0; h < 2; ++h)
      koff[c][h] = (c * 16 + lr) * 64 + (((h * 4 + lg) ^ (lr & 7)) * 8);
  int voff[4][2][2];
#pragma unroll
  for (int dt = 0; dt < 4; ++dt)
#pragma unroll
    for (int ks = 0; ks < 2; ++ks) {
      const int g0 = (ks * 4 + (lg >> 1)) ^ (lr & 7);
      const int g1 = (ks * 4 + 2 + (lg >> 1)) ^ (lr & 7);
      voff[dt][ks][0] = (dt * 16 + lr) * 64 + g0 * 8 + (lg & 1) * 4;
      voff[dt][ks][1] = (dt * 16 + lr) * 64 + g1 * 8 + (lg & 1) * 4;
    }

  float mrun = -INFINITY, lrun = 0.f;
  f32x4 acc[4] = {};
  const int nt = btile + 1;  // >= 17

  STAGE(0, 0);
  STAGE(1, 1);
  STAGE(2, 2);  // 6 outstanding

  for (int kt = 0; kt < nt; ++kt) {
    const int cb = kt & 3;
    const int ahead = btile - kt;
    if (ahead >= 3) {
      STAGE((kt + 3) & 3, kt + 3);
      asm volatile("s_waitcnt vmcnt(6)" ::: "memory");
    } else if (ahead == 2) {
      asm volatile("s_waitcnt vmcnt(4)" ::: "memory");
    } else if (ahead == 1) {
      asm volatile("s_waitcnt vmcnt(2)" ::: "memory");
    } else {
      asm volatile("s_waitcnt vmcnt(0)" ::: "memory");
    }
    __builtin_amdgcn_s_barrier();
    asm volatile("" ::: "memory");

    if (kt <= myq) {
      const int kb = kt * 64;
      f32x4 s[4] = {};
      bf16x8 kf[4][2];
#pragma unroll
      for (int c = 0; c < 4; ++c)
#pragma unroll
        for (int h = 0; h < 2; ++h)
          kf[c][h] = *reinterpret_cast<const bf16x8*>(&Ks[cb][koff[c][h]]);
#pragma unroll
      for (int c = 0; c < 4; ++c)
#pragma unroll
        for (int h = 0; h < 2; ++h)
          s[c] = __builtin_amdgcn_mfma_f32_16x16x32_bf16(kf[c][h], qf[h], s[c], 0, 0, 0);

      if (kt == myq) {
#pragma unroll
        for (int c = 0; c < 4; ++c)
#pragma unroll
          for (int j = 0; j < 4; ++j) {
            const int k = kb + c * 16 + lg * 4 + j;
            if (k > q) s[c][j] = -INFINITY;
          }
      }
      float tm = -INFINITY;
#pragma unroll
      for (int c = 0; c < 4; ++c)
#pragma unroll
        for (int j = 0; j < 4; ++j) tm = fmaxf(tm, s[c][j]);
      tm = fmaxf(tm, __shfl_xor(tm, 16, 64));
      tm = fmaxf(tm, __shfl_xor(tm, 32, 64));
      if (!__all(tm <= mrun + 8.f)) {
        const float mnew = fmaxf(mrun, tm);
        const float fac = exp2f(mrun - mnew);
        lrun *= fac;
#pragma unroll
        for (int dt = 0; dt < 4; ++dt)
#pragma unroll
          for (int j = 0; j < 4; ++j) acc[dt][j] *= fac;
        mrun = mnew;
      }
      float tsum = 0.f;
#pragma unroll
      for (int c = 0; c < 4; ++c)
#pragma unroll
        for (int j = 0; j < 4; ++j) {
          const float p = exp2f(s[c][j] - mrun);
          s[c][j] = p;
          tsum += p;
        }
      tsum += __shfl_xor(tsum, 16, 64);
      tsum += __shfl_xor(tsum, 32, 64);
      lrun += tsum;

      bf16x8 pb[2];
#pragma unroll
      for (int ks = 0; ks < 2; ++ks) {
        bf16x8 t8;
#pragma unroll
        for (int e = 0; e < 8; ++e) t8[e] = (__bf16)s[ks * 2 + (e >> 2)][e & 3];
        pb[ks] = t8;
      }
#pragma unroll
      for (int dt = 0; dt < 4; ++dt) {
#pragma unroll
        for (int ks = 0; ks < 2; ++ks) {
          uint2 vlo = *reinterpret_cast<const uint2*>(&Vs[cb][voff[dt][ks][0]]);
          uint2 vhi = *reinterpret_cast<const uint2*>(&Vs[cb][voff[dt][ks][1]]);
          uint4 u;
          u.x = vlo.x; u.y = vlo.y; u.z = vhi.x; u.w = vhi.y;
          bf16x8 vf = __builtin_bit_cast(bf16x8, u);
          acc[dt] = __builtin_amdgcn_mfma_f32_16x16x32_bf16(vf, pb[ks], acc[dt], 0, 0, 0);
        }
      }
    }
    asm volatile("" ::: "memory");
    __builtin_amdgcn_s_barrier();
  }
#undef STAGE

  const int b = bh >> 4, h = bh & (NHEAD - 1);
  const float inv = 1.0f / lrun;
  unsigned short* orow = O + (((size_t)(b * T_SEQ + q)) << 10) + h * HDIM + lg * 4;
#pragma unroll
  for (int dt = 0; dt < 4; ++dt) {
    ushortx4 o4;
#pragma unroll
    for (int j = 0; j < 4; ++j) o4[j] = f2bf(acc[dt][j] * inv);
    *reinterpret_cast<ushortx4*>(orow + dt * 16) = o4;
  }
}

extern "C" void kernel_launch(void* const* d_in, const int* in_sizes, int n_in,
                              void* d_out, int out_size, void* d_ws, size_t ws_size,
                              hipStream_t stream) {
  const float* x  = (const float*)d_in[0];
  const float* Wq = (const float*)d_in[1];
  const float* Wk = (const float*)d_in[2];
  const float* Wv = (const float*)d_in[3];
  const float* Wo = (const float*)d_in[4];
  const float* bo = (const float*)d_in[5];
  float* out = (float*)d_out;

  const int M = 2 * T_SEQ;          // 4096
  const int NXD = DMODEL * DMODEL;  // 1048576
  const int NX = M * DMODEL;        // 4194304

  unsigned short* ws = (unsigned short*)d_ws;
  unsigned short* xb  = ws;
  unsigned short* Wqb = xb + NX;                 // Wq,Wk,Wv,Wo contiguous
  unsigned short* Wob = Wqb + 3 * (size_t)NXD;
  unsigned short* Qb  = Wqb + 4 * (size_t)NXD;   // [b,h,t,d], pre-scaled 0.125*log2e
  unsigned short* Kbf = Qb + NX;                 // [b,h,t,d]
  unsigned short* Vtb = Kbf + NX;                // [b,h,d,t]
  unsigned short* Ob  = Vtb + NX;                // [b,t,D]

  cast_all<<<(NX + 4 * NXD) / 1024, 256, 0, stream>>>(x, Wq, Wk, Wv, Wo, xb);

  dim3 gq(256, 3);
  gemm_qkv<<<gq, 256, 0, stream>>>(xb, Wqb, Qb, Kbf, Vtb);

  flash_attn<<<512, 512, 0, stream>>>(Qb, Kbf, Vtb, Ob);

  dim3 gg(DMODEL / 128, M / 128);
  gemm_proj<<<gg, 256, 0, stream>>>(Ob, Wob, out, bo);
}